// Round 5
// baseline (246.735 us; speedup 1.0000x reference)
//
#include <hip/hip_runtime.h>

// y = W @ x + bias, W in COO (rows sorted), fp32.
// R10: R5 structure byte-for-byte (best measured: 77.9us spmv) with ONE
// knob: CHUNK 8->4 (SPAN 1024, RMAX 512, 12500 blocks). Decisive probe
// between the two remaining theories for the 78us wall:
//   (a) per-CU L1-miss-handling THROUGHPUT (~3.4cy/line-miss at the TCP):
//       identical total miss count => neutral (74-82us) => roofline.
//   (b) wave-level outstanding-miss CONCURRENCY: 2x blocks + shorter
//       per-wave TA bursts => more misses in flight => 60-70us.
// Path matrix already closed: L1-allocating(77.9) < glc(87.4) < LDS-DMA
// (87.9); structure matrix: monolithic(77.9) < persistent-pipelined(89.6)
// < CHUNK=16(91.9). Streams stay nontemporal (R8 showed plain regressed).

constexpr int       CHUNK = 4;                        // nnz per thread
constexpr int       BLOCK = 256;
constexpr long long SPAN  = (long long)BLOCK * CHUNK; // 1024 nnz per block
constexpr int       RMAX  = 512;                      // LDS acc slots (2 KB)

typedef float vfloat4 __attribute__((ext_vector_type(4)));
typedef int   vint4   __attribute__((ext_vector_type(4)));

__global__ void init_y_bias(const float* __restrict__ bias,
                            float* __restrict__ y, int n) {
    int i = blockIdx.x * blockDim.x + threadIdx.x;
    if (i < n) y[i] = bias[i];
}

__device__ __forceinline__ void lds_add(float* p, float v) {
    // workgroup-scope relaxed fp add -> ds_add_f32 (no TCC involvement)
    __hip_atomic_fetch_add(p, v, __ATOMIC_RELAXED, __HIP_MEMORY_SCOPE_WORKGROUP);
}

__global__ __launch_bounds__(BLOCK) void spmv_coo_lds(
        const float* __restrict__ vals,
        const float* __restrict__ x,
        const int*   __restrict__ rows,
        const int*   __restrict__ cols,
        const float* __restrict__ bias,
        float*       __restrict__ y,
        long long nnz) {
    __shared__ float acc[RMAX];
    const int tid = threadIdx.x;
    const long long b0 = (long long)blockIdx.x * SPAN;
    if (b0 >= nnz) return;                       // whole block exits uniformly
    const long long bend = (b0 + SPAN < nnz) ? (b0 + SPAN) : nnz;
    const bool full = (b0 + SPAN) <= nnz;        // block-uniform

    // ---- issue streaming loads FIRST: latency overlaps the prologue ----
    float v[CHUNK]; int r[CHUNK]; int c[CHUNK];
    const long long i0 = b0 + (long long)tid * CHUNK;
    if (full) {
        const vfloat4* v4 = reinterpret_cast<const vfloat4*>(vals + i0);
        const vint4*   r4 = reinterpret_cast<const vint4*>(rows + i0);
        const vint4*   c4 = reinterpret_cast<const vint4*>(cols + i0);
        #pragma unroll
        for (int q = 0; q < CHUNK / 4; ++q) {
            vfloat4 vv = __builtin_nontemporal_load(v4 + q);
            vint4   rr = __builtin_nontemporal_load(r4 + q);
            vint4   cc = __builtin_nontemporal_load(c4 + q);
            #pragma unroll
            for (int j = 0; j < 4; ++j) {
                v[4*q+j] = vv[j];
                r[4*q+j] = rr[j];
                c[4*q+j] = cc[j];
            }
        }
    }

    // ---- prologue: fixed-size zero (independent of row-range loads) ----
    #pragma unroll
    for (int i = tid; i < RMAX; i += BLOCK) acc[i] = 0.f;
    const int r0    = rows[b0];
    const int rl    = rows[bend - 1];
    const int range = rl - r0 + 1;
    __syncthreads();

    if (range <= RMAX) {
        if (full) {
            // gathers up front (MLP); x stays L1/L2-cacheable
            float g[CHUNK];
            #pragma unroll
            for (int k = 0; k < CHUNK; ++k) g[k] = x[c[k]];

            int   cur = r[0];
            float sum = v[0] * g[0];
            #pragma unroll
            for (int k = 1; k < CHUNK; ++k) {
                if (r[k] != cur) {               // row boundary: flush run
                    lds_add(&acc[cur - r0], sum);
                    cur = r[k];
                    sum = 0.f;
                }
                sum += v[k] * g[k];
            }
            lds_add(&acc[cur - r0], sum);
        } else if (i0 < bend) {
            // scalar partial-block path
            int   cur = rows[i0];
            float sum = 0.f;
            long long kend = (i0 + CHUNK < bend) ? (i0 + CHUNK) : bend;
            for (long long k = i0; k < kend; ++k) {
                int rk = rows[k];
                if (rk != cur) { lds_add(&acc[cur - r0], sum); sum = 0.f; cur = rk; }
                sum += vals[k] * x[cols[k]];
            }
            lds_add(&acc[cur - r0], sum);
        }
        __syncthreads();

        // ---- coalesced epilogue: interior rows exclusively owned ----
        for (int i = tid; i < range; i += BLOCK) {
            int   rr = r0 + i;
            float a  = acc[i];
            if (rr == r0 || rr == rl) {
                if (a != 0.f) atomicAdd(&y[rr], a);  // may span block boundary
            } else {
                y[rr] = bias[rr] + a;                // plain coalesced store
            }
        }
    } else {
        // pathological row-gap fallback: per-thread global atomics
        if (i0 < bend) {
            if (full) {
                float g[CHUNK];
                #pragma unroll
                for (int k = 0; k < CHUNK; ++k) g[k] = x[c[k]];
                int   cur = r[0];
                float sum = v[0] * g[0];
                #pragma unroll
                for (int k = 1; k < CHUNK; ++k) {
                    if (r[k] != cur) { atomicAdd(&y[cur], sum); sum = 0.f; cur = r[k]; }
                    sum += v[k] * g[k];
                }
                atomicAdd(&y[cur], sum);
            } else {
                int   cur = rows[i0];
                float sum = 0.f;
                long long kend = (i0 + CHUNK < bend) ? (i0 + CHUNK) : bend;
                for (long long k = i0; k < kend; ++k) {
                    int rk = rows[k];
                    if (rk != cur) { atomicAdd(&y[cur], sum); sum = 0.f; cur = rk; }
                    sum += vals[k] * x[cols[k]];
                }
                atomicAdd(&y[cur], sum);
            }
        }
    }
}

extern "C" void kernel_launch(void* const* d_in, const int* in_sizes, int n_in,
                              void* d_out, int out_size, void* d_ws, size_t ws_size,
                              hipStream_t stream) {
    const float* vals = (const float*)d_in[0];
    const float* x    = (const float*)d_in[1];
    const float* bias = (const float*)d_in[2];
    const int*   rows = (const int*)d_in[3];
    const int*   cols = (const int*)d_in[4];
    float* y = (float*)d_out;

    const long long nnz = in_sizes[0];
    const int n_rows    = in_sizes[2];   // len(bias) == n_rows

    // 1) y = bias (covers empty gap-rows + rows receiving boundary atomics)
    {
        int threads = 256;
        int blocks  = (n_rows + threads - 1) / threads;
        init_y_bias<<<blocks, threads, 0, stream>>>(bias, y, n_rows);
    }

    // 2) block-local LDS-accumulated COO reduce
    {
        long long blocks = (nnz + SPAN - 1) / SPAN;
        spmv_coo_lds<<<(int)blocks, BLOCK, 0, stream>>>(
            vals, x, rows, cols, bias, y, nnz);
    }
}

// Round 6
// 207.658 us; speedup vs baseline: 1.1882x; 1.1882x over previous
//
#include <hip/hip_runtime.h>

// y = W @ x + bias, W in COO (rows sorted), fp32.
// R11 = R5 restored (best measured: 77.9us spmv / 208us total).
// Six-round experiment matrix concluded this config is the optimum of a
// per-CU L1-miss-concurrency-bound regime:
//   - gather demand: ~48K line-misses/CU over x (800KB, L2-resident,
//     L1 hit ~4%); measured in-flight ~64 lines/CU = TCP miss-queue cap.
//   - CHUNK: 4 -> 118us (MLP under cap), 8 -> 77.9us, 16 -> 91.9us
//     (compiler serializes, occupancy drops). Bracketed optimum.
//   - gather path: L1-allocating (77.9) < glc (87.4) < LDS-DMA (87.9);
//     all share the same per-CU miss pool.
//   - structure: monolithic (77.9) < persistent-pipelined (89.6);
//     8 co-resident blocks/CU already saturate the pool.
//   - streams: nontemporal < plain (R8) — nt keeps L1 clean for x.
// HBM 12%, VALU 5%, bank conflicts 0: no other resource near a wall.

constexpr int       CHUNK = 8;                        // nnz per thread
constexpr int       BLOCK = 256;
constexpr long long SPAN  = (long long)BLOCK * CHUNK; // 2048 nnz per block
constexpr int       RMAX  = 768;                      // LDS acc slots (3 KB)

typedef float vfloat4 __attribute__((ext_vector_type(4)));
typedef int   vint4   __attribute__((ext_vector_type(4)));

__global__ void init_y_bias(const float* __restrict__ bias,
                            float* __restrict__ y, int n) {
    int i = blockIdx.x * blockDim.x + threadIdx.x;
    if (i < n) y[i] = bias[i];
}

__device__ __forceinline__ void lds_add(float* p, float v) {
    // workgroup-scope relaxed fp add -> ds_add_f32 (no TCC involvement)
    __hip_atomic_fetch_add(p, v, __ATOMIC_RELAXED, __HIP_MEMORY_SCOPE_WORKGROUP);
}

__global__ __launch_bounds__(BLOCK) void spmv_coo_lds(
        const float* __restrict__ vals,
        const float* __restrict__ x,
        const int*   __restrict__ rows,
        const int*   __restrict__ cols,
        const float* __restrict__ bias,
        float*       __restrict__ y,
        long long nnz) {
    __shared__ float acc[RMAX];
    const int tid = threadIdx.x;
    const long long b0 = (long long)blockIdx.x * SPAN;
    if (b0 >= nnz) return;                       // whole block exits uniformly
    const long long bend = (b0 + SPAN < nnz) ? (b0 + SPAN) : nnz;
    const bool full = (b0 + SPAN) <= nnz;        // block-uniform

    // ---- issue streaming loads FIRST: latency overlaps the prologue ----
    float v[CHUNK]; int r[CHUNK]; int c[CHUNK];
    const long long i0 = b0 + (long long)tid * CHUNK;
    if (full) {
        const vfloat4* v4 = reinterpret_cast<const vfloat4*>(vals + i0);
        const vint4*   r4 = reinterpret_cast<const vint4*>(rows + i0);
        const vint4*   c4 = reinterpret_cast<const vint4*>(cols + i0);
        #pragma unroll
        for (int q = 0; q < CHUNK / 4; ++q) {
            vfloat4 vv = __builtin_nontemporal_load(v4 + q);
            vint4   rr = __builtin_nontemporal_load(r4 + q);
            vint4   cc = __builtin_nontemporal_load(c4 + q);
            #pragma unroll
            for (int j = 0; j < 4; ++j) {
                v[4*q+j] = vv[j];
                r[4*q+j] = rr[j];
                c[4*q+j] = cc[j];
            }
        }
    }

    // ---- prologue: fixed-size zero (independent of row-range loads) ----
    #pragma unroll
    for (int i = tid; i < RMAX; i += BLOCK) acc[i] = 0.f;
    const int r0    = rows[b0];
    const int rl    = rows[bend - 1];
    const int range = rl - r0 + 1;
    __syncthreads();

    if (range <= RMAX) {
        if (full) {
            // gathers up front (MLP); x stays L1/L2-cacheable
            float g[CHUNK];
            #pragma unroll
            for (int k = 0; k < CHUNK; ++k) g[k] = x[c[k]];

            int   cur = r[0];
            float sum = v[0] * g[0];
            #pragma unroll
            for (int k = 1; k < CHUNK; ++k) {
                if (r[k] != cur) {               // row boundary: flush run
                    lds_add(&acc[cur - r0], sum);
                    cur = r[k];
                    sum = 0.f;
                }
                sum += v[k] * g[k];
            }
            lds_add(&acc[cur - r0], sum);
        } else if (i0 < bend) {
            // scalar partial-block path
            int   cur = rows[i0];
            float sum = 0.f;
            long long kend = (i0 + CHUNK < bend) ? (i0 + CHUNK) : bend;
            for (long long k = i0; k < kend; ++k) {
                int rk = rows[k];
                if (rk != cur) { lds_add(&acc[cur - r0], sum); sum = 0.f; cur = rk; }
                sum += vals[k] * x[cols[k]];
            }
            lds_add(&acc[cur - r0], sum);
        }
        __syncthreads();

        // ---- coalesced epilogue: interior rows exclusively owned ----
        for (int i = tid; i < range; i += BLOCK) {
            int   rr = r0 + i;
            float a  = acc[i];
            if (rr == r0 || rr == rl) {
                if (a != 0.f) atomicAdd(&y[rr], a);  // may span block boundary
            } else {
                y[rr] = bias[rr] + a;                // plain coalesced store
            }
        }
    } else {
        // pathological row-gap fallback: per-thread global atomics
        if (i0 < bend) {
            if (full) {
                float g[CHUNK];
                #pragma unroll
                for (int k = 0; k < CHUNK; ++k) g[k] = x[c[k]];
                int   cur = r[0];
                float sum = v[0] * g[0];
                #pragma unroll
                for (int k = 1; k < CHUNK; ++k) {
                    if (r[k] != cur) { atomicAdd(&y[cur], sum); sum = 0.f; cur = r[k]; }
                    sum += v[k] * g[k];
                }
                atomicAdd(&y[cur], sum);
            } else {
                int   cur = rows[i0];
                float sum = 0.f;
                long long kend = (i0 + CHUNK < bend) ? (i0 + CHUNK) : bend;
                for (long long k = i0; k < kend; ++k) {
                    int rk = rows[k];
                    if (rk != cur) { atomicAdd(&y[cur], sum); sum = 0.f; cur = rk; }
                    sum += vals[k] * x[cols[k]];
                }
                atomicAdd(&y[cur], sum);
            }
        }
    }
}

extern "C" void kernel_launch(void* const* d_in, const int* in_sizes, int n_in,
                              void* d_out, int out_size, void* d_ws, size_t ws_size,
                              hipStream_t stream) {
    const float* vals = (const float*)d_in[0];
    const float* x    = (const float*)d_in[1];
    const float* bias = (const float*)d_in[2];
    const int*   rows = (const int*)d_in[3];
    const int*   cols = (const int*)d_in[4];
    float* y = (float*)d_out;

    const long long nnz = in_sizes[0];
    const int n_rows    = in_sizes[2];   // len(bias) == n_rows

    // 1) y = bias (covers empty gap-rows + rows receiving boundary atomics)
    {
        int threads = 256;
        int blocks  = (n_rows + threads - 1) / threads;
        init_y_bias<<<blocks, threads, 0, stream>>>(bias, y, n_rows);
    }

    // 2) block-local LDS-accumulated COO reduce
    {
        long long blocks = (nnz + SPAN - 1) / SPAN;
        spmv_coo_lds<<<(int)blocks, BLOCK, 0, stream>>>(
            vals, x, rows, cols, bias, y, nnz);
    }
}